// Round 4
// baseline (118.723 us; speedup 1.0000x reference)
//
#include <hip/hip_runtime.h>
#include <math.h>

// MatchNet: MLP(6->20->20->20->8, tanh) then 150-iter PDHG LP per row.
// R13: TLP experiment. Calibrated law across R10/R11/R12: wall ~= slots/wave
// x ~3.3ns at 1 wave/SIMD -- i.e. 7-8 cyc per-wave issue cadence, 3.5-4x the
// 2-cyc SIMD-32 issue floor. Single-wave-per-SIMD cannot hide dep latency /
// issue arbitration / DPP hazards. Fix: block=32 (half-active wave64) ->
// 2048 waves = 2 waves/SIMD; co-resident waves interleave and fill the
// cadence bubbles. COMPUTE CODE BYTE-IDENTICAL TO R12 (verified bit-exact,
// absmax 0.001953125) -- only launch geometry + LDS staging stride changed.
// VGPR 132 -> 3 waves/SIMD allowed; LDS 5KiB x 8 blocks/CU = 40KiB. If this
// nulls, the SIMD issue port is saturated -> next lever is slot reduction
// (4-lane/row). N_ITERS must stay 150.

#define N_ITERS 150
typedef float f2 __attribute__((ext_vector_type(2)));
typedef float f4 __attribute__((ext_vector_type(4)));

__device__ __forceinline__ float fast_tanh(float a) {
    float e = __expf(2.0f * a);
    return 1.0f - 2.0f * __builtin_amdgcn_rcpf(e + 1.0f);
}

__device__ __forceinline__ float dpp_swap(float v) {
    // quad_perm [1,0,3,2]: lane pairs (2k,2k+1) exchange
    union { float f; int i; } u;
    u.f = v;
    u.i = __builtin_amdgcn_update_dpp(0, u.i, 0xB1, 0xF, 0xF, true);
    return u.f;
}

__device__ __forceinline__ f2 fma2(f2 a, f2 b, f2 c) {
    return __builtin_elementwise_fma(a, b, c);
}

__global__ void __launch_bounds__(32)
__attribute__((amdgpu_waves_per_eu(2)))
matchnet_kernel(
    const float* __restrict__ X,
    const float* __restrict__ W1, const float* __restrict__ b1,
    const float* __restrict__ W2, const float* __restrict__ b2,
    const float* __restrict__ W3, const float* __restrict__ b3,
    const float* __restrict__ W4, const float* __restrict__ b4,
    float* __restrict__ out, int B)
{
    // Transposed weights: tW1[j*8+i] (i<6, pad 8), tW2/tW3[j*20+i], tW4[k*20+i]
    __shared__ alignas(16) float tW1[160], tW2[400], tW3[400], tW4[160];
    __shared__ alignas(16) float sb1[20], sb2[20], sb3[20], sb4[8];
    {
        int tid = threadIdx.x;
        for (int idx = tid; idx < 120; idx += 32) { int i = idx / 20, j = idx % 20; tW1[j * 8 + i] = W1[idx]; }
        for (int idx = tid; idx < 400; idx += 32) { int i = idx / 20, j = idx % 20; tW2[j * 20 + i] = W2[idx]; }
        for (int idx = tid; idx < 400; idx += 32) { int i = idx / 20, j = idx % 20; tW3[j * 20 + i] = W3[idx]; }
        for (int idx = tid; idx < 160; idx += 32) { int i = idx / 8,  k = idx % 8;  tW4[k * 20 + i] = W4[idx]; }
        if (tid < 20) { sb1[tid] = b1[tid]; sb2[tid] = b2[tid]; sb3[tid] = b3[tid]; }
        if (tid < 8) sb4[tid] = b4[tid];
    }
    __syncthreads();

    int gidx = blockIdx.x * 32 + threadIdx.x;
    int row = gidx >> 1;
    if (row >= B) return;
    const bool isOdd = (gidx & 1) != 0;
    const int jb = isOdd ? 10 : 0;   // this lane's neuron range (layers 1-3)
    const int kb = isOdd ? 4 : 0;    // this lane's output range (layer 4)

    float bb0 = X[row * 6 + 0], bb1 = X[row * 6 + 1], bb2 = X[row * 6 + 2];
    float bb3 = X[row * 6 + 3], bb4 = X[row * 6 + 4], bb5 = X[row * 6 + 5];

    // --- MLP, neuron-split across the lane pair (byte-identical to R10) ---
    float hA[10], hB[10];   // absolute h[0..9], h[10..19] (both lanes)
    {
        // L1: 10 neurons, inputs bb0..bb5 (full in both lanes) -> bit-exact
        float acc[10];
        const f2* bv = (const f2*)&sb1[jb];
        #pragma unroll
        for (int p = 0; p < 5; p++) { f2 b = bv[p]; acc[2 * p] = b.x; acc[2 * p + 1] = b.y; }
        #pragma unroll
        for (int n = 0; n < 10; n++) {
            int j = jb + n;
            f4 w0 = *(const f4*)&tW1[j * 8];
            f2 w1 = *(const f2*)&tW1[j * 8 + 4];
            float a = acc[n];
            a = fmaf(bb0, w0.x, a); a = fmaf(bb1, w0.y, a); a = fmaf(bb2, w0.z, a);
            a = fmaf(bb3, w0.w, a); a = fmaf(bb4, w1.x, a); a = fmaf(bb5, w1.y, a);
            acc[n] = fast_tanh(a);
        }
        #pragma unroll
        for (int n = 0; n < 10; n++) {
            float t = dpp_swap(acc[n]);
            hA[n] = isOdd ? t : acc[n];
            hB[n] = isOdd ? acc[n] : t;
        }
    }
    #pragma unroll
    for (int layer = 0; layer < 2; layer++) {
        const float* tw = layer ? tW3 : tW2;
        const float* sb = layer ? sb3 : sb2;
        float acc[10];
        const f2* bv = (const f2*)&sb[jb];
        #pragma unroll
        for (int p = 0; p < 5; p++) { f2 b = bv[p]; acc[2 * p] = b.x; acc[2 * p + 1] = b.y; }
        #pragma unroll
        for (int n = 0; n < 10; n++) {
            int j = jb + n;
            const f4* w = (const f4*)&tw[j * 20];
            f4 w0 = w[0], w1 = w[1], w2 = w[2], w3 = w[3], w4 = w[4];
            float a = acc[n];
            a = fmaf(hA[0], w0.x, a); a = fmaf(hA[1], w0.y, a);
            a = fmaf(hA[2], w0.z, a); a = fmaf(hA[3], w0.w, a);
            a = fmaf(hA[4], w1.x, a); a = fmaf(hA[5], w1.y, a);
            a = fmaf(hA[6], w1.z, a); a = fmaf(hA[7], w1.w, a);
            a = fmaf(hA[8], w2.x, a); a = fmaf(hA[9], w2.y, a);
            a = fmaf(hB[0], w2.z, a); a = fmaf(hB[1], w2.w, a);
            a = fmaf(hB[2], w3.x, a); a = fmaf(hB[3], w3.y, a);
            a = fmaf(hB[4], w3.z, a); a = fmaf(hB[5], w3.w, a);
            a = fmaf(hB[6], w4.x, a); a = fmaf(hB[7], w4.y, a);
            a = fmaf(hB[8], w4.z, a); a = fmaf(hB[9], w4.w, a);
            acc[n] = fast_tanh(a);
        }
        #pragma unroll
        for (int n = 0; n < 10; n++) {
            float t = dpp_swap(acc[n]);
            hA[n] = isOdd ? t : acc[n];
            hB[n] = isOdd ? acc[n] : t;
        }
    }
    // L4: this lane's 4 outputs == exactly its z components (no exchange)
    float oz0, oz1, oz2, oz3;
    {
        f4 b = *(const f4*)&sb4[kb];
        float acc[4] = {b.x, b.y, b.z, b.w};
        #pragma unroll
        for (int n = 0; n < 4; n++) {
            int k = kb + n;
            const f4* w = (const f4*)&tW4[k * 20];
            f4 w0 = w[0], w1 = w[1], w2 = w[2], w3 = w[3], w4 = w[4];
            float a = acc[n];
            a = fmaf(hA[0], w0.x, a); a = fmaf(hA[1], w0.y, a);
            a = fmaf(hA[2], w0.z, a); a = fmaf(hA[3], w0.w, a);
            a = fmaf(hA[4], w1.x, a); a = fmaf(hA[5], w1.y, a);
            a = fmaf(hA[6], w1.z, a); a = fmaf(hA[7], w1.w, a);
            a = fmaf(hA[8], w2.x, a); a = fmaf(hA[9], w2.y, a);
            a = fmaf(hB[0], w2.z, a); a = fmaf(hB[1], w2.w, a);
            a = fmaf(hB[2], w3.x, a); a = fmaf(hB[3], w3.y, a);
            a = fmaf(hB[4], w3.z, a); a = fmaf(hB[5], w3.w, a);
            a = fmaf(hB[6], w4.x, a); a = fmaf(hB[7], w4.y, a);
            a = fmaf(hB[8], w4.z, a); a = fmaf(hB[9], w4.w, a);
            acc[n] = a;
        }
        oz0 = acc[0]; oz1 = acc[1]; oz2 = acc[2]; oz3 = acc[3];
    }

    // --- constants ---
    const float tau  = 0.18898223650461363f;   // 1/sqrt(28)
    const float c    = 0.03571428571428571f;   // tau*sigma = 1/28
    const float tauC = 1.8898223650461363f;    // tau * control_strength(10)
    const f2 C2    = {c, c};
    const f2 NEGC2 = {-c, -c};
    const f2 TWO2  = {2.f, 2.f};

    // --- PDHG state, packed into f2 pairs (this lane's 4 components) ---
    f2 OZ01 = {oz0, oz1}, OZ23 = {oz2, oz3};
    f2 OT01 = {tau - oz0, tau - oz1}, OT23 = {tau - oz2, tau - oz3};
    f2 TI01 = OT01, TI23 = OT23;
    f2 X01  = {fmaxf(oz0, 0.f), fmaxf(oz1, 0.f)};
    f2 X23  = {fmaxf(oz2, 0.f), fmaxf(oz3, 0.f)};
    f2 XB01 = X01, XB23 = X23;

    // dual-row constants: even rows (0,2,1) -> (cb0,cb2,cb1); odd (4,3,5)
    float cb0 = c * bb0, cb1 = c * bb1, cb2 = c * bb2;
    float cb3 = c * bb3, cb4 = c * bb4, cb5 = c * bb5;
    f2 CB01 = {isOdd ? cb4 : cb0, isOdd ? cb3 : cb2};
    float cbq2 = isOdd ? cb5 : cb1;
    f2 Y01 = {0.f, 0.f};
    float Yq2 = 0.f;

    #pragma unroll 1
    for (int it = 0; it < N_ITERS; it++) {
        // xb exchange (4 dpp): rxb_i = partner's xb component i
        float rxb0 = dpp_swap(XB01.x), rxb1 = dpp_swap(XB01.y);
        float rxb2 = dpp_swap(XB23.x), rxb3 = dpp_swap(XB23.y);

        // s-sums: even lane (s0,s2,s1), odd (s4,s3,s5) — exact R9 orders
        f2 R12 = {rxb1, rxb2};
        f2 R32 = {rxb3, rxb2};
        f2 AE = XB01 + R12;                 // (op_a, op_e)
        f2 BC = XB23 + R32;                 // (op_b, op_c)
        float op_d = isOdd ? BC.y : BC.x;
        float op_f = isOdd ? rxb3 : XB01.x;
        f2 DF = {op_d, op_f};
        f2 S01 = AE + DF;                   // (sq0, sq1)
        f2 GH = (f2){XB01.y, XB01.x} + (f2){XB23.y, XB23.x};  // (op_g, op_h)
        float op_i = isOdd ? GH.y : GH.x;
        float sq2 = op_i + rxb0;

        // Y updates: Y = max(0, fma(c,s,Y) - cb)
        f2 tY = fma2(C2, S01, Y01) - CB01;
        Y01.x = fmaxf(0.f, tY.x);
        Y01.y = fmaxf(0.f, tY.y);
        float tY2 = fmaf(c, sq2, Yq2) - cbq2;
        Yq2 = fmaxf(0.f, tY2);

        // Y exchange (3 dpp): e gets (Y4,Y3,Y5); o gets (Y0,Y2,Y1)
        float rY0 = dpp_swap(Y01.x), rY1 = dpp_swap(Y01.y), rY2 = dpp_swap(Yq2);

        // column sums: even cols 0-3, odd cols 4-7 — exact R9 orders
        float op_j = Y01.x + rY2;           // e: Y0+Y5 | o: Y4+Y1
        float op_k = isOdd ? Yq2 : Y01.y;   // e: Y2    | o: Y5
        float op_l = Y01.y + rY0;           // e: Y2+Y4 | o: Y3+Y0
        float op_p = isOdd ? 0.f : Yq2;     // e: Y1    | o: 0
        f2 C01 = (f2){op_j, op_l} + (f2){op_k, op_p};  // (colq0, colq1)
        float op_m = Y01.x + rY0;           // e: Y0+Y4 | o: Y4+Y0 (=col7)
        float op_n = rY1 + Yq2;             // e: Y3+Y1 (=col3) | o: Y2+Y5 (=col6)
        float op_o = op_m + rY1;            // e: Y0+Y4+Y3 (=col2) | o: garbage
        f2 C23 = {isOdd ? op_n : op_o, isOdd ? op_m : op_n};  // (colq2, colq3)

        // TI = max(t, fma(-c, xb, TI))
        f2 u01 = fma2(NEGC2, XB01, TI01);
        f2 u23 = fma2(NEGC2, XB23, TI23);
        TI01.x = fmaxf(OT01.x, u01.x); TI01.y = fmaxf(OT01.y, u01.y);
        TI23.x = fmaxf(OT23.x, u23.x); TI23.y = fmaxf(OT23.y, u23.y);

        // d = (x + TI) - col
        f2 D01 = (X01 + TI01) - C01;
        f2 D23 = (X23 + TI23) - C23;

        // nsq: scalar 4-term chain + cross-lane add (exact R9 order)
        float nl = D01.x * D01.x;
        nl = fmaf(D01.y, D01.y, nl);
        nl = fmaf(D23.x, D23.x, nl);
        nl = fmaf(D23.y, D23.y, nl);
        float rn = dpp_swap(nl);
        float nsq = nl + rn;

        // scale = max(0, 1 - tauC*rsq(nsq)); rsq(0)=inf -> 0 == ref clamp
        float rs = __builtin_amdgcn_rsqf(nsq);
        float scale = fmaxf(0.f, fmaf(-tauC, rs, 1.f));

        // xn + xb commit
        f2 SC = {scale, scale};
        f2 XN01 = fma2(SC, D01, OZ01);
        f2 XN23 = fma2(SC, D23, OZ23);
        XB01 = fma2(TWO2, XN01, -X01);
        XB23 = fma2(TWO2, XN23, -X23);
        X01 = XN01; X23 = XN23;
    }

    // even lane: comps 0-3 at out4[row*2]; odd: comps 4-7 at out4[row*2+1]
    float4* out4 = (float4*)out;
    out4[gidx] = make_float4(X01.x, X01.y, X23.x, X23.y);
}

extern "C" void kernel_launch(void* const* d_in, const int* in_sizes, int n_in,
                              void* d_out, int out_size, void* d_ws, size_t ws_size,
                              hipStream_t stream) {
    const float* X  = (const float*)d_in[0];
    const float* W1 = (const float*)d_in[1];
    const float* b1 = (const float*)d_in[2];
    const float* W2 = (const float*)d_in[3];
    const float* b2 = (const float*)d_in[4];
    const float* W3 = (const float*)d_in[5];
    const float* b3 = (const float*)d_in[6];
    const float* W4 = (const float*)d_in[7];
    const float* b4 = (const float*)d_in[8];
    float* out = (float*)d_out;

    int B = in_sizes[0] / 6;
    const int block = 32;   // half-active wave64 -> 2x waves -> 2 waves/SIMD
    long long threads = (long long)B * 2;
    int grid = (int)((threads + block - 1) / block);
    hipLaunchKernelGGL(matchnet_kernel, dim3(grid), dim3(block), 0, stream,
                       X, W1, b1, W2, b2, W3, b3, W4, b4, out, B);
}

// Round 6
// 98.706 us; speedup vs baseline: 1.2028x; 1.2028x over previous
//
#include <hip/hip_runtime.h>
#include <math.h>

// MatchNet: MLP(6->20->20->20->8, tanh) then 150-iter PDHG LP per row.
// R15 = R12 (verified best, 98.9us, absmax 0.001953125) restored, plus ONE
// audited micro-shave (GH pair-marshal scalarized; no dpp, no Y change).
// SESSION RULES (hard-won):
//  - R14 FAILED (absmax 0.52) with semantically-identical source whose only
//    difference was INLINED dpp_swap encouraging DPP-fold into consumers.
//    => DPP ONLY as standalone named temporaries (rxb*, rY*, rn). Never
//    inline dpp_swap into an expression.
//  - Law (R10-R13): wall ~= instr/wave x ~3.4ns at 1024 full waves (1/SIMD);
//    rate ILP-independent (R11); TLP self-defeating (R13: half-waves 2x
//    instr for +40% rate). Only lever: emitted instructions per wave.
//  - v_pk_* only where pairs persist with zero marshalling (verified in R12).
// BIT-EXACT vs R9/R12 trajectory; output absmax must be 0.001953125.
// N_ITERS must stay 150 (R6: trajectory moves ~0.5 between it 100 and 150).

#define N_ITERS 150
typedef float f2 __attribute__((ext_vector_type(2)));
typedef float f4 __attribute__((ext_vector_type(4)));

__device__ __forceinline__ float fast_tanh(float a) {
    float e = __expf(2.0f * a);
    return 1.0f - 2.0f * __builtin_amdgcn_rcpf(e + 1.0f);
}

__device__ __forceinline__ float dpp_swap(float v) {
    // quad_perm [1,0,3,2]: lane pairs (2k,2k+1) exchange
    union { float f; int i; } u;
    u.f = v;
    u.i = __builtin_amdgcn_update_dpp(0, u.i, 0xB1, 0xF, 0xF, true);
    return u.f;
}

__device__ __forceinline__ f2 fma2(f2 a, f2 b, f2 c) {
    return __builtin_elementwise_fma(a, b, c);
}

__global__ void __launch_bounds__(64)
__attribute__((amdgpu_waves_per_eu(1, 1)))
matchnet_kernel(
    const float* __restrict__ X,
    const float* __restrict__ W1, const float* __restrict__ b1,
    const float* __restrict__ W2, const float* __restrict__ b2,
    const float* __restrict__ W3, const float* __restrict__ b3,
    const float* __restrict__ W4, const float* __restrict__ b4,
    float* __restrict__ out, int B)
{
    // Transposed weights: tW1[j*8+i] (i<6, pad 8), tW2/tW3[j*20+i], tW4[k*20+i]
    __shared__ alignas(16) float tW1[160], tW2[400], tW3[400], tW4[160];
    __shared__ alignas(16) float sb1[20], sb2[20], sb3[20], sb4[8];
    {
        int tid = threadIdx.x;
        for (int idx = tid; idx < 120; idx += 64) { int i = idx / 20, j = idx % 20; tW1[j * 8 + i] = W1[idx]; }
        for (int idx = tid; idx < 400; idx += 64) { int i = idx / 20, j = idx % 20; tW2[j * 20 + i] = W2[idx]; }
        for (int idx = tid; idx < 400; idx += 64) { int i = idx / 20, j = idx % 20; tW3[j * 20 + i] = W3[idx]; }
        for (int idx = tid; idx < 160; idx += 64) { int i = idx / 8,  k = idx % 8;  tW4[k * 20 + i] = W4[idx]; }
        if (tid < 20) { sb1[tid] = b1[tid]; sb2[tid] = b2[tid]; sb3[tid] = b3[tid]; }
        if (tid < 8) sb4[tid] = b4[tid];
    }
    __syncthreads();

    int gidx = blockIdx.x * blockDim.x + threadIdx.x;
    int row = gidx >> 1;
    if (row >= B) return;
    const bool isOdd = (gidx & 1) != 0;
    const int jb = isOdd ? 10 : 0;   // this lane's neuron range (layers 1-3)
    const int kb = isOdd ? 4 : 0;    // this lane's output range (layer 4)

    float bb0 = X[row * 6 + 0], bb1 = X[row * 6 + 1], bb2 = X[row * 6 + 2];
    float bb3 = X[row * 6 + 3], bb4 = X[row * 6 + 4], bb5 = X[row * 6 + 5];

    // --- MLP, neuron-split across the lane pair (byte-identical to R10) ---
    float hA[10], hB[10];   // absolute h[0..9], h[10..19] (both lanes)
    {
        // L1: 10 neurons, inputs bb0..bb5 (full in both lanes) -> bit-exact
        float acc[10];
        const f2* bv = (const f2*)&sb1[jb];
        #pragma unroll
        for (int p = 0; p < 5; p++) { f2 b = bv[p]; acc[2 * p] = b.x; acc[2 * p + 1] = b.y; }
        #pragma unroll
        for (int n = 0; n < 10; n++) {
            int j = jb + n;
            f4 w0 = *(const f4*)&tW1[j * 8];
            f2 w1 = *(const f2*)&tW1[j * 8 + 4];
            float a = acc[n];
            a = fmaf(bb0, w0.x, a); a = fmaf(bb1, w0.y, a); a = fmaf(bb2, w0.z, a);
            a = fmaf(bb3, w0.w, a); a = fmaf(bb4, w1.x, a); a = fmaf(bb5, w1.y, a);
            acc[n] = fast_tanh(a);
        }
        #pragma unroll
        for (int n = 0; n < 10; n++) {
            float t = dpp_swap(acc[n]);
            hA[n] = isOdd ? t : acc[n];
            hB[n] = isOdd ? acc[n] : t;
        }
    }
    #pragma unroll
    for (int layer = 0; layer < 2; layer++) {
        const float* tw = layer ? tW3 : tW2;
        const float* sb = layer ? sb3 : sb2;
        float acc[10];
        const f2* bv = (const f2*)&sb[jb];
        #pragma unroll
        for (int p = 0; p < 5; p++) { f2 b = bv[p]; acc[2 * p] = b.x; acc[2 * p + 1] = b.y; }
        #pragma unroll
        for (int n = 0; n < 10; n++) {
            int j = jb + n;
            const f4* w = (const f4*)&tw[j * 20];
            f4 w0 = w[0], w1 = w[1], w2 = w[2], w3 = w[3], w4 = w[4];
            float a = acc[n];
            a = fmaf(hA[0], w0.x, a); a = fmaf(hA[1], w0.y, a);
            a = fmaf(hA[2], w0.z, a); a = fmaf(hA[3], w0.w, a);
            a = fmaf(hA[4], w1.x, a); a = fmaf(hA[5], w1.y, a);
            a = fmaf(hA[6], w1.z, a); a = fmaf(hA[7], w1.w, a);
            a = fmaf(hA[8], w2.x, a); a = fmaf(hA[9], w2.y, a);
            a = fmaf(hB[0], w2.z, a); a = fmaf(hB[1], w2.w, a);
            a = fmaf(hB[2], w3.x, a); a = fmaf(hB[3], w3.y, a);
            a = fmaf(hB[4], w3.z, a); a = fmaf(hB[5], w3.w, a);
            a = fmaf(hB[6], w4.x, a); a = fmaf(hB[7], w4.y, a);
            a = fmaf(hB[8], w4.z, a); a = fmaf(hB[9], w4.w, a);
            acc[n] = fast_tanh(a);
        }
        #pragma unroll
        for (int n = 0; n < 10; n++) {
            float t = dpp_swap(acc[n]);
            hA[n] = isOdd ? t : acc[n];
            hB[n] = isOdd ? acc[n] : t;
        }
    }
    // L4: this lane's 4 outputs == exactly its z components (no exchange)
    float oz0, oz1, oz2, oz3;
    {
        f4 b = *(const f4*)&sb4[kb];
        float acc[4] = {b.x, b.y, b.z, b.w};
        #pragma unroll
        for (int n = 0; n < 4; n++) {
            int k = kb + n;
            const f4* w = (const f4*)&tW4[k * 20];
            f4 w0 = w[0], w1 = w[1], w2 = w[2], w3 = w[3], w4 = w[4];
            float a = acc[n];
            a = fmaf(hA[0], w0.x, a); a = fmaf(hA[1], w0.y, a);
            a = fmaf(hA[2], w0.z, a); a = fmaf(hA[3], w0.w, a);
            a = fmaf(hA[4], w1.x, a); a = fmaf(hA[5], w1.y, a);
            a = fmaf(hA[6], w1.z, a); a = fmaf(hA[7], w1.w, a);
            a = fmaf(hA[8], w2.x, a); a = fmaf(hA[9], w2.y, a);
            a = fmaf(hB[0], w2.z, a); a = fmaf(hB[1], w2.w, a);
            a = fmaf(hB[2], w3.x, a); a = fmaf(hB[3], w3.y, a);
            a = fmaf(hB[4], w3.z, a); a = fmaf(hB[5], w3.w, a);
            a = fmaf(hB[6], w4.x, a); a = fmaf(hB[7], w4.y, a);
            a = fmaf(hB[8], w4.z, a); a = fmaf(hB[9], w4.w, a);
            acc[n] = a;
        }
        oz0 = acc[0]; oz1 = acc[1]; oz2 = acc[2]; oz3 = acc[3];
    }

    // --- constants ---
    const float tau  = 0.18898223650461363f;   // 1/sqrt(28)
    const float c    = 0.03571428571428571f;   // tau*sigma = 1/28
    const float tauC = 1.8898223650461363f;    // tau * control_strength(10)
    const f2 C2    = {c, c};
    const f2 NEGC2 = {-c, -c};
    const f2 TWO2  = {2.f, 2.f};

    // --- PDHG state, packed into f2 pairs (this lane's 4 components) ---
    f2 OZ01 = {oz0, oz1}, OZ23 = {oz2, oz3};
    f2 OT01 = {tau - oz0, tau - oz1}, OT23 = {tau - oz2, tau - oz3};
    f2 TI01 = OT01, TI23 = OT23;
    f2 X01  = {fmaxf(oz0, 0.f), fmaxf(oz1, 0.f)};
    f2 X23  = {fmaxf(oz2, 0.f), fmaxf(oz3, 0.f)};
    f2 XB01 = X01, XB23 = X23;

    // dual-row constants: even rows (0,2,1) -> (cb0,cb2,cb1); odd (4,3,5)
    float cb0 = c * bb0, cb1 = c * bb1, cb2 = c * bb2;
    float cb3 = c * bb3, cb4 = c * bb4, cb5 = c * bb5;
    f2 CB01 = {isOdd ? cb4 : cb0, isOdd ? cb3 : cb2};
    float cbq2 = isOdd ? cb5 : cb1;
    f2 Y01 = {0.f, 0.f};
    float Yq2 = 0.f;

    #pragma unroll 1
    for (int it = 0; it < N_ITERS; it++) {
        // xb exchange (4 dpp, STANDALONE named movs -- see R14 rule)
        float rxb0 = dpp_swap(XB01.x), rxb1 = dpp_swap(XB01.y);
        float rxb2 = dpp_swap(XB23.x), rxb3 = dpp_swap(XB23.y);

        // s-sums: even lane (s0,s2,s1), odd (s4,s3,s5) — exact R9 orders
        f2 R12 = {rxb1, rxb2};
        f2 R32 = {rxb3, rxb2};
        f2 AE = XB01 + R12;                 // (op_a, op_e)
        f2 BC = XB23 + R32;                 // (op_b, op_c)
        float op_d = isOdd ? BC.y : BC.x;
        float op_f = isOdd ? rxb3 : XB01.x;
        f2 DF = {op_d, op_f};
        f2 S01 = AE + DF;                   // (sq0, sq1)
        float op_g = XB01.y + XB23.y;       // e: xb1+xb3 (odd: garbage)
        float op_h = XB01.x + XB23.x;       // o: xb4+xb6 (even: garbage)
        float op_i = isOdd ? op_h : op_g;
        float sq2 = op_i + rxb0;

        // Y updates: Y = max(0, fma(c,s,Y) - cb)
        f2 tY = fma2(C2, S01, Y01) - CB01;
        Y01.x = fmaxf(0.f, tY.x);
        Y01.y = fmaxf(0.f, tY.y);
        float tY2 = fmaf(c, sq2, Yq2) - cbq2;
        Yq2 = fmaxf(0.f, tY2);

        // Y exchange (3 dpp, standalone): e gets (Y4,Y3,Y5); o gets (Y0,Y2,Y1)
        float rY0 = dpp_swap(Y01.x), rY1 = dpp_swap(Y01.y), rY2 = dpp_swap(Yq2);

        // column sums: even cols 0-3, odd cols 4-7 — exact R9 orders
        float op_j = Y01.x + rY2;           // e: Y0+Y5 | o: Y4+Y1
        float op_k = isOdd ? Yq2 : Y01.y;   // e: Y2    | o: Y5
        float op_l = Y01.y + rY0;           // e: Y2+Y4 | o: Y3+Y0
        float op_p = isOdd ? 0.f : Yq2;     // e: Y1    | o: 0
        f2 C01 = (f2){op_j, op_l} + (f2){op_k, op_p};  // (colq0, colq1)
        float op_m = Y01.x + rY0;           // e: Y0+Y4 | o: Y4+Y0 (=col7)
        float op_n = rY1 + Yq2;             // e: Y3+Y1 (=col3) | o: Y2+Y5 (=col6)
        float op_o = op_m + rY1;            // e: Y0+Y4+Y3 (=col2) | o: garbage
        f2 C23 = {isOdd ? op_n : op_o, isOdd ? op_m : op_n};  // (colq2, colq3)

        // TI = max(t, fma(-c, xb, TI))
        f2 u01 = fma2(NEGC2, XB01, TI01);
        f2 u23 = fma2(NEGC2, XB23, TI23);
        TI01.x = fmaxf(OT01.x, u01.x); TI01.y = fmaxf(OT01.y, u01.y);
        TI23.x = fmaxf(OT23.x, u23.x); TI23.y = fmaxf(OT23.y, u23.y);

        // d = (x + TI) - col
        f2 D01 = (X01 + TI01) - C01;
        f2 D23 = (X23 + TI23) - C23;

        // nsq: scalar 4-term chain + cross-lane add (exact R9 order)
        float nl = D01.x * D01.x;
        nl = fmaf(D01.y, D01.y, nl);
        nl = fmaf(D23.x, D23.x, nl);
        nl = fmaf(D23.y, D23.y, nl);
        float rn = dpp_swap(nl);
        float nsq = nl + rn;

        // scale = max(0, 1 - tauC*rsq(nsq)); rsq(0)=inf -> 0 == ref clamp
        float rs = __builtin_amdgcn_rsqf(nsq);
        float scale = fmaxf(0.f, fmaf(-tauC, rs, 1.f));

        // xn + xb commit
        f2 SC = {scale, scale};
        f2 XN01 = fma2(SC, D01, OZ01);
        f2 XN23 = fma2(SC, D23, OZ23);
        XB01 = fma2(TWO2, XN01, -X01);
        XB23 = fma2(TWO2, XN23, -X23);
        X01 = XN01; X23 = XN23;
    }

    // even lane: comps 0-3 at out4[row*2]; odd: comps 4-7 at out4[row*2+1]
    float4* out4 = (float4*)out;
    out4[gidx] = make_float4(X01.x, X01.y, X23.x, X23.y);
}

extern "C" void kernel_launch(void* const* d_in, const int* in_sizes, int n_in,
                              void* d_out, int out_size, void* d_ws, size_t ws_size,
                              hipStream_t stream) {
    const float* X  = (const float*)d_in[0];
    const float* W1 = (const float*)d_in[1];
    const float* b1 = (const float*)d_in[2];
    const float* W2 = (const float*)d_in[3];
    const float* b2 = (const float*)d_in[4];
    const float* W3 = (const float*)d_in[5];
    const float* b3 = (const float*)d_in[6];
    const float* W4 = (const float*)d_in[7];
    const float* b4 = (const float*)d_in[8];
    float* out = (float*)d_out;

    int B = in_sizes[0] / 6;
    const int block = 64;
    long long threads = (long long)B * 2;
    int grid = (int)((threads + block - 1) / block);
    hipLaunchKernelGGL(matchnet_kernel, dim3(grid), dim3(block), 0, stream,
                       X, W1, b1, W2, b2, W3, b3, W4, b4, out, B);
}